// Round 2
// baseline (392.521 us; speedup 1.0000x reference)
//
#include <hip/hip_runtime.h>
#include <hip/hip_bf16.h>
#include <math.h>

#define NEGINF (-9000000000000000.0f)

constexpr int B_    = 8;
constexpr int N_    = 2048;
constexpr int FIN   = 256;
constexpr int FOUT  = 128;
constexpr int K1_ROWS = 16;
constexpr int TI    = 8;

__device__ __forceinline__ void fma4(float4& acc, float s, const float4& v) {
    acc.x += s * v.x; acc.y += s * v.y; acc.z += s * v.z; acc.w += s * v.w;
}
__device__ __forceinline__ float dot4(const float4& u, const float4& v) {
    return u.x * v.x + u.y * v.y + u.z * v.z + u.w * v.w;
}

// ---------------------------------------------------------------------------
// K1: Wh = x @ W (16 rows/block) + f1/f2 = Wh . a1/a2 fused in epilogue.
// Thread = (1 row, 8 dims): per 4k -> 1 ds_read_b128 (x) + 8 coalesced float4
// W loads (L2-hot) + 32 FMA. LDS pipe nearly idle; VALU/VMEM-bound.
// ---------------------------------------------------------------------------
__global__ __launch_bounds__(256) void k1_wh(const float* __restrict__ x,
                                             const float* __restrict__ W,
                                             const float* __restrict__ a,
                                             float* __restrict__ Wh,
                                             float* __restrict__ f1,
                                             float* __restrict__ f2) {
    __shared__ float xs[K1_ROWS * FIN];    // 16 KB
    __shared__ float fs[2][K1_ROWS][16];   // 2 KB: f1/f2 partials
    const int tid = threadIdx.x;
    const long r0 = (long)blockIdx.x * K1_ROWS;  // flat row = b*N + i

    // stage 16 consecutive x rows (16 KB contiguous) into LDS
    {
        const float4* x4  = (const float4*)(x + r0 * FIN);
        float4*       xs4 = (float4*)xs;
#pragma unroll
        for (int it = 0; it < (K1_ROWS * FIN / 4) / 256; ++it)
            xs4[tid + it * 256] = x4[tid + it * 256];
    }
    __syncthreads();

    const int rg = tid >> 4;   // row 0..15
    const int dg = tid & 15;   // dims dg*8 .. dg*8+7
    float4 acc0 = make_float4(0.f, 0.f, 0.f, 0.f);
    float4 acc1 = make_float4(0.f, 0.f, 0.f, 0.f);

    const float4* W4  = (const float4*)W;             // [k][32 quads]
    const float4* xr4 = (const float4*)(xs + rg * FIN);
    for (int k4 = 0; k4 < FIN / 4; ++k4) {
        float4 xv = xr4[k4];  // 16-lane broadcast ds_read_b128
#pragma unroll
        for (int kk = 0; kk < 4; ++kk) {
            const int k = 4 * k4 + kk;
            float4 w0 = W4[k * 32 + dg * 2];
            float4 w1 = W4[k * 32 + dg * 2 + 1];
            float xk = (kk == 0) ? xv.x : (kk == 1) ? xv.y : (kk == 2) ? xv.z : xv.w;
            fma4(acc0, xk, w0);
            fma4(acc1, xk, w1);
        }
    }

    // store Wh (coalesced: 16 lanes cover one 512B row)
    float4* Wh4 = (float4*)(Wh + (r0 + rg) * FOUT);
    Wh4[dg * 2]     = acc0;
    Wh4[dg * 2 + 1] = acc1;

    // f1/f2 partials from the accumulators (no Wa kernel needed)
    const float4* a4 = (const float4*)a;
    float p1 = dot4(acc0, a4[dg * 2])      + dot4(acc1, a4[dg * 2 + 1]);
    float p2 = dot4(acc0, a4[32 + dg * 2]) + dot4(acc1, a4[32 + dg * 2 + 1]);
    fs[0][rg][dg] = p1;
    fs[1][rg][dg] = p2;
    __syncthreads();

    if (tid < 32) {
        const int which = tid >> 4, r = tid & 15;
        float s = 0.f;
#pragma unroll
        for (int d = 0; d < 16; ++d) s += fs[which][r][d];
        (which ? f2 : f1)[r0 + r] = s;
    }
}

// ---------------------------------------------------------------------------
// K2: fused masked-softmax attention + P@Wh + ELU. One block per 8 rows.
// b = blockIdx&7 pins each batch's 1MB Wh slab to one XCD L2.
// Phase B thread = (j-slice, 8 dims): p via ds_read_b128 broadcast, j-groups
// interleaved (j = it*64 + jg*4) so the 4 distinct wave addresses hit
// disjoint banks. LDS = 64 KB -> 2 blocks/CU.
// ---------------------------------------------------------------------------
__global__ __launch_bounds__(256) void k2_attn(const int* __restrict__ adj,
                                               const float* __restrict__ Wh,
                                               const float* __restrict__ f1,
                                               const float* __restrict__ f2,
                                               float* __restrict__ out) {
    __shared__ float p[TI][N_];   // 64 KB: unnormalized softmax weights
    __shared__ float rsum[TI];

    const int tid  = threadIdx.x;
    const int b    = blockIdx.x & 7;
    const int i0   = (blockIdx.x >> 3) * TI;
    const int lane = tid & 63;
    const int wave = tid >> 6;

    const float4* f2b4 = (const float4*)(f2 + (size_t)b * N_);

    // ---- Phase A: scores + max + exp; wave w does rows 2w, 2w+1 ----
#pragma unroll
    for (int rr = 0; rr < 2; ++rr) {
        const int ti = wave * 2 + rr;
        const int i  = i0 + ti;
        const float f1i = f1[(size_t)b * N_ + i];
        const int4* arow4 = (const int4*)(adj + ((size_t)b * N_ + i) * N_);
        float4* prow4 = (float4*)&p[ti][0];

        float m = NEGINF;
        for (int j4 = lane; j4 < N_ / 4; j4 += 64) {
            int4   av = arow4[j4];
            float4 fv = f2b4[j4];
            float e0 = f1i + fv.x; e0 = (e0 >= 0.f) ? e0 : 2.f * e0; if (av.x <= 0) e0 = NEGINF;
            float e1 = f1i + fv.y; e1 = (e1 >= 0.f) ? e1 : 2.f * e1; if (av.y <= 0) e1 = NEGINF;
            float e2 = f1i + fv.z; e2 = (e2 >= 0.f) ? e2 : 2.f * e2; if (av.z <= 0) e2 = NEGINF;
            float e3 = f1i + fv.w; e3 = (e3 >= 0.f) ? e3 : 2.f * e3; if (av.w <= 0) e3 = NEGINF;
            prow4[j4] = make_float4(e0, e1, e2, e3);
            m = fmaxf(m, fmaxf(fmaxf(e0, e1), fmaxf(e2, e3)));
        }
#pragma unroll
        for (int o = 32; o; o >>= 1) m = fmaxf(m, __shfl_xor(m, o));

        float s = 0.f;
        for (int j4 = lane; j4 < N_ / 4; j4 += 64) {
            float4 pv = prow4[j4];
            pv.x = __expf(pv.x - m);
            pv.y = __expf(pv.y - m);
            pv.z = __expf(pv.z - m);
            pv.w = __expf(pv.w - m);
            prow4[j4] = pv;
            s += pv.x + pv.y + pv.z + pv.w;
        }
#pragma unroll
        for (int o = 32; o; o >>= 1) s += __shfl_xor(s, o);
        if (lane == 0) rsum[ti] = s;
    }
    __syncthreads();

    // ---- Phase B: acc[t][0:8] += p[t][j] * Wh[b,j, dg*8 .. dg*8+7] ----
    const int jg = tid >> 4;  // 0..15
    const int dg = tid & 15;  // dim octet
    float4 a0[TI], a1[TI];
#pragma unroll
    for (int t = 0; t < TI; ++t) {
        a0[t] = make_float4(0.f, 0.f, 0.f, 0.f);
        a1[t] = make_float4(0.f, 0.f, 0.f, 0.f);
    }

    const float4* WhB = (const float4*)(Wh + (size_t)b * N_ * FOUT);
    for (int it = 0; it < N_ / 64; ++it) {
        const int j0 = it * 64 + jg * 4;
        float4 pv[TI];
#pragma unroll
        for (int t = 0; t < TI; ++t)
            pv[t] = *(const float4*)&p[t][j0];   // ds_read_b128, 16-lane bcast
#pragma unroll
        for (int q = 0; q < 4; ++q) {
            const float4 w0 = WhB[(size_t)(j0 + q) * 32 + dg * 2];
            const float4 w1 = WhB[(size_t)(j0 + q) * 32 + dg * 2 + 1];
#pragma unroll
            for (int t = 0; t < TI; ++t) {
                const float pj = (q == 0) ? pv[t].x : (q == 1) ? pv[t].y
                               : (q == 2) ? pv[t].z : pv[t].w;
                fma4(a0[t], pj, w0);
                fma4(a1[t], pj, w1);
            }
        }
    }
    __syncthreads();  // done reading p; reuse its space for the reduction

    // red[jg][t][dim]: 16*8*128 floats = 64 KB (aliases p)
    float* red = &p[0][0];
#pragma unroll
    for (int t = 0; t < TI; ++t) {
        float4* dst = (float4*)&red[jg * (TI * FOUT) + t * FOUT + dg * 8];
        dst[0] = a0[t];
        dst[1] = a1[t];
    }
    __syncthreads();

    // ---- Epilogue: combine 16 j-slices, /rsum, ELU, store ----
    const int orow = tid >> 5;   // 0..7
    const int d4   = tid & 31;   // dim quad
    float4 tot = make_float4(0.f, 0.f, 0.f, 0.f);
#pragma unroll
    for (int g = 0; g < 16; ++g) {
        float4 v = *(const float4*)&red[g * (TI * FOUT) + orow * FOUT + d4 * 4];
        tot.x += v.x; tot.y += v.y; tot.z += v.z; tot.w += v.w;
    }
    const float inv = 1.f / rsum[orow];
    tot.x *= inv; tot.y *= inv; tot.z *= inv; tot.w *= inv;
    tot.x = (tot.x > 0.f) ? tot.x : expm1f(tot.x);
    tot.y = (tot.y > 0.f) ? tot.y : expm1f(tot.y);
    tot.z = (tot.z > 0.f) ? tot.z : expm1f(tot.z);
    tot.w = (tot.w > 0.f) ? tot.w : expm1f(tot.w);

    float4* out4 = (float4*)out;
    out4[((size_t)b * N_ + i0 + orow) * (FOUT / 4) + d4] = tot;
}

// ---------------------------------------------------------------------------
extern "C" void kernel_launch(void* const* d_in, const int* in_sizes, int n_in,
                              void* d_out, int out_size, void* d_ws, size_t ws_size,
                              hipStream_t stream) {
    const float* x   = (const float*)d_in[0];
    const int*   adj = (const int*)d_in[1];
    const float* W   = (const float*)d_in[2];
    const float* a   = (const float*)d_in[3];
    float* out = (float*)d_out;

    // workspace layout (fp32): Wh | f1 | f2   (~8.1 MB)
    float* Wh = (float*)d_ws;
    float* f1 = Wh + (size_t)B_ * N_ * FOUT;
    float* f2 = f1 + (size_t)B_ * N_;

    hipLaunchKernelGGL(k1_wh, dim3(B_ * N_ / K1_ROWS), dim3(256), 0, stream,
                       x, W, a, Wh, f1, f2);
    hipLaunchKernelGGL(k2_attn, dim3(B_ * N_ / TI), dim3(256), 0, stream,
                       adj, Wh, f1, f2, out);
}

// Round 3
// 282.710 us; speedup vs baseline: 1.3884x; 1.3884x over previous
//
#include <hip/hip_runtime.h>
#include <hip/hip_bf16.h>
#include <math.h>

#define NEGINF (-9000000000000000.0f)

constexpr int B_   = 8;
constexpr int N_   = 2048;
constexpr int FIN  = 256;
constexpr int FOUT = 128;
constexpr int TI   = 16;           // k2 rows per block (= MFMA M)
constexpr int PPAD = 8;            // bf16 pad per p row
constexpr int PROW = N_ + PPAD;    // 2056
constexpr int WPAD = 8;
constexpr int WROW = FIN + WPAD;   // 264 (k1 LDS row stride)

typedef __attribute__((ext_vector_type(8))) short bf16x8;
typedef __attribute__((ext_vector_type(4))) float f32x4;

static __device__ __forceinline__ unsigned short f2bf(float f) {
    __hip_bfloat16 h = __float2bfloat16(f);
    return *reinterpret_cast<unsigned short*>(&h);
}
static __device__ __forceinline__ float bf2f(unsigned short u) {
    unsigned int v = ((unsigned int)u) << 16;
    return *reinterpret_cast<float*>(&v);
}

// ---------------------------------------------------------------------------
// K0: Wt[n][k] = bf16(W[k][n])  (dim-major weight, 64 KB)
// 128 blocks (one per output dim), 256 threads (one per k). Writes coalesced.
// ---------------------------------------------------------------------------
__global__ __launch_bounds__(256) void k0_wt(const float* __restrict__ W,
                                             unsigned short* __restrict__ Wt) {
    const int n = blockIdx.x;   // 0..127
    const int k = threadIdx.x;  // 0..255
    Wt[n * FIN + k] = f2bf(W[k * FOUT + n]);
}

// ---------------------------------------------------------------------------
// K1: WhT[b][d][j] = sum_k W[k][d] * x[j][k]   via MFMA 16x16x32 bf16.
// D = A*B with A[m=d][k], B[k][n=row]: A from Wt LDS, B from x LDS (bf16).
// Block = 64 rows; wave w: m-tiles {2w,2w+1} x 4 n-tiles x 8 K-steps.
// ---------------------------------------------------------------------------
__global__ __launch_bounds__(256) void k1_wh(const float* __restrict__ x,
                                             const unsigned short* __restrict__ Wt,
                                             unsigned short* __restrict__ WhT) {
    __shared__ unsigned short wt[FOUT * WROW];  // 67,584 B
    __shared__ unsigned short xs[64 * WROW];    // 33,792 B
    const int tid = threadIdx.x;
    const long r0 = (long)blockIdx.x * 64;      // global flat row base

    // stage Wt (bf16, contiguous) -> padded LDS rows
    {
        const int4* src = (const int4*)Wt;      // 8 bf16 per int4, 4096 total
        for (int i = tid; i < FOUT * FIN / 8; i += 256) {
            int row = i >> 5;                   // 32 chunks per row
            int c   = i & 31;
            *(int4*)&wt[row * WROW + c * 8] = src[i];
        }
    }
    // stage x rows (fp32 -> bf16) -> padded LDS rows
    {
        const float4* xsrc = (const float4*)(x + r0 * FIN);  // 4096 float4
        for (int i = tid; i < 64 * FIN / 4; i += 256) {
            float4 v = xsrc[i];
            int row = i >> 6;                   // 64 float4 per row
            int c   = i & 63;
            ushort4 u;
            u.x = f2bf(v.x); u.y = f2bf(v.y); u.z = f2bf(v.z); u.w = f2bf(v.w);
            *(ushort4*)&xs[row * WROW + c * 4] = u;
        }
    }
    __syncthreads();

    const int wave = tid >> 6, lane = tid & 63;
    const int quad = lane >> 4, l16 = lane & 15;

    f32x4 acc[2][4];
#pragma unroll
    for (int a = 0; a < 2; ++a)
#pragma unroll
        for (int b = 0; b < 4; ++b) acc[a][b] = {0.f, 0.f, 0.f, 0.f};

#pragma unroll
    for (int ks = 0; ks < FIN / 32; ++ks) {
        const int kof = ks * 32 + quad * 8;
        bf16x8 afr[2], bfr[4];
#pragma unroll
        for (int a = 0; a < 2; ++a) {
            const int d = (wave * 2 + a) * 16 + l16;
            afr[a] = *(const bf16x8*)&wt[d * WROW + kof];
        }
#pragma unroll
        for (int b = 0; b < 4; ++b) {
            const int r = b * 16 + l16;
            bfr[b] = *(const bf16x8*)&xs[r * WROW + kof];
        }
#pragma unroll
        for (int a = 0; a < 2; ++a)
#pragma unroll
            for (int b = 0; b < 4; ++b)
                acc[a][b] = __builtin_amdgcn_mfma_f32_16x16x32_bf16(
                    afr[a], bfr[b], acc[a][b], 0, 0, 0);
    }

    // store D (m=d, n=row) -> WhT[b][d][j] bf16
    const long bb = r0 / N_;
    const long jb = r0 % N_;
    unsigned short* dst = WhT + bb * (long)FOUT * N_;
#pragma unroll
    for (int a = 0; a < 2; ++a)
#pragma unroll
        for (int b = 0; b < 4; ++b) {
            const long j = jb + b * 16 + l16;
#pragma unroll
            for (int r = 0; r < 4; ++r) {
                const int d = (wave * 2 + a) * 16 + quad * 4 + r;
                dst[(long)d * N_ + j] = f2bf(acc[a][b][r]);
            }
        }
}

// ---------------------------------------------------------------------------
// K1b: f1[bj] = sum_d a1[d]*WhT[b][d][j];  f2 likewise with a2. fp32.
// 64 blocks x 256 threads = one thread per (b,j). Coalesced per-d rows.
// ---------------------------------------------------------------------------
__global__ __launch_bounds__(256) void k1b_f(const unsigned short* __restrict__ WhT,
                                             const float* __restrict__ a,
                                             float* __restrict__ f1,
                                             float* __restrict__ f2) {
    __shared__ float a1s[FOUT], a2s[FOUT];
    const int tid = threadIdx.x;
    if (tid < FOUT) { a1s[tid] = a[tid]; a2s[tid] = a[FOUT + tid]; }
    __syncthreads();
    const long jflat = (long)blockIdx.x * 256 + tid;
    const long b = jflat / N_, j = jflat % N_;
    const unsigned short* src = WhT + b * (long)FOUT * N_ + j;
    float s1 = 0.f, s2 = 0.f;
#pragma unroll
    for (int d = 0; d < FOUT; ++d) {
        float w = bf2f(src[(long)d * N_]);
        s1 += w * a1s[d];
        s2 += w * a2s[d];
    }
    f1[jflat] = s1;
    f2[jflat] = s2;
}

// ---------------------------------------------------------------------------
// K2: fused masked softmax + P@WhT (MFMA) + ELU. 16 rows/block, 1024 blocks.
// Phase A: e in registers (fp32), exp, store P bf16 to LDS (A-frag layout).
// Phase B: wave w computes O[16][dims 32w..32w+31]: per K-step 1 ds_read_b128
// + 2 global b128 (WhT, L2-hot) + 2 MFMA. LDS ~66 KB -> 2 blocks/CU.
// ---------------------------------------------------------------------------
__global__ __launch_bounds__(256) void k2_attn(const int* __restrict__ adj,
                                               const unsigned short* __restrict__ WhT,
                                               const float* __restrict__ f1,
                                               const float* __restrict__ f2,
                                               float* __restrict__ out) {
    __shared__ unsigned short p[TI * PROW];   // 65,792 B
    __shared__ float rsum[TI];

    const int tid  = threadIdx.x;
    const int b    = blockIdx.x & 7;          // XCD-pinned batch
    const int i0   = (blockIdx.x >> 3) * TI;
    const int wave = tid >> 6, lane = tid & 63;
    const int quad = lane >> 4, l16 = lane & 15;

    const float4* f2b4 = (const float4*)(f2 + (size_t)b * N_);

    // ---- Phase A: wave w handles rows 4w..4w+3 ----
    for (int rr = 0; rr < 4; ++rr) {
        const int ti = wave * 4 + rr;
        const int i  = i0 + ti;
        const float f1i = f1[(size_t)b * N_ + i];
        const int4* arow4 = (const int4*)(adj + ((size_t)b * N_ + i) * (size_t)N_);

        int4   av[8];
        float4 fv[8];
#pragma unroll
        for (int it = 0; it < 8; ++it) {
            av[it] = arow4[lane + it * 64];
            fv[it] = f2b4[lane + it * 64];
        }
        float4 e[8];
        float m = NEGINF;
#pragma unroll
        for (int it = 0; it < 8; ++it) {
            const float4 t = fv[it];
            float e0 = f1i + t.x; e0 = (e0 >= 0.f) ? e0 : 2.f * e0; if (av[it].x <= 0) e0 = NEGINF;
            float e1 = f1i + t.y; e1 = (e1 >= 0.f) ? e1 : 2.f * e1; if (av[it].y <= 0) e1 = NEGINF;
            float e2 = f1i + t.z; e2 = (e2 >= 0.f) ? e2 : 2.f * e2; if (av[it].z <= 0) e2 = NEGINF;
            float e3 = f1i + t.w; e3 = (e3 >= 0.f) ? e3 : 2.f * e3; if (av[it].w <= 0) e3 = NEGINF;
            e[it] = make_float4(e0, e1, e2, e3);
            m = fmaxf(m, fmaxf(fmaxf(e0, e1), fmaxf(e2, e3)));
        }
#pragma unroll
        for (int o = 32; o; o >>= 1) m = fmaxf(m, __shfl_xor(m, o));

        float s = 0.f;
        unsigned short* pr = &p[ti * PROW];
#pragma unroll
        for (int it = 0; it < 8; ++it) {
            const float p0 = __expf(e[it].x - m);
            const float p1 = __expf(e[it].y - m);
            const float p2 = __expf(e[it].z - m);
            const float p3 = __expf(e[it].w - m);
            s += (p0 + p1) + (p2 + p3);
            ushort4 u;
            u.x = f2bf(p0); u.y = f2bf(p1); u.z = f2bf(p2); u.w = f2bf(p3);
            *(ushort4*)&pr[(lane + it * 64) * 4] = u;
        }
#pragma unroll
        for (int o = 32; o; o >>= 1) s += __shfl_xor(s, o);
        if (lane == 0) rsum[ti] = s;
    }
    __syncthreads();

    // ---- Phase B: O[m=ti][n=dim] = P @ Wh. Wave w -> dims 32w..32w+31 ----
    const int n0 = wave * 32;
    const unsigned short* whb = WhT + (size_t)b * FOUT * N_;
    const unsigned short* pA  = &p[l16 * PROW];              // A row m = l16
    const unsigned short* wB0 = whb + (size_t)(n0 + l16) * N_;
    const unsigned short* wB1 = whb + (size_t)(n0 + 16 + l16) * N_;

    f32x4 acc0 = {0.f, 0.f, 0.f, 0.f}, acc1 = {0.f, 0.f, 0.f, 0.f};
#pragma unroll 4
    for (int ks = 0; ks < N_ / 32; ++ks) {
        const int kof = ks * 32 + quad * 8;
        bf16x8 afr = *(const bf16x8*)&pA[kof];
        bf16x8 b0  = *(const bf16x8*)&wB0[kof];
        bf16x8 b1  = *(const bf16x8*)&wB1[kof];
        acc0 = __builtin_amdgcn_mfma_f32_16x16x32_bf16(afr, b0, acc0, 0, 0, 0);
        acc1 = __builtin_amdgcn_mfma_f32_16x16x32_bf16(afr, b1, acc1, 0, 0, 0);
    }

    // ---- Epilogue: /rowsum, ELU, store (row m = quad*4+r, col n = l16) ----
#pragma unroll
    for (int r = 0; r < 4; ++r) {
        const int m = quad * 4 + r;
        const float inv = 1.f / rsum[m];
        float v0 = acc0[r] * inv;
        float v1 = acc1[r] * inv;
        v0 = (v0 > 0.f) ? v0 : expm1f(v0);
        v1 = (v1 > 0.f) ? v1 : expm1f(v1);
        const size_t base = ((size_t)b * N_ + i0 + m) * FOUT + n0;
        out[base + l16]      = v0;
        out[base + 16 + l16] = v1;
    }
}

// ---------------------------------------------------------------------------
extern "C" void kernel_launch(void* const* d_in, const int* in_sizes, int n_in,
                              void* d_out, int out_size, void* d_ws, size_t ws_size,
                              hipStream_t stream) {
    const float* x   = (const float*)d_in[0];
    const int*   adj = (const int*)d_in[1];
    const float* W   = (const float*)d_in[2];
    const float* a   = (const float*)d_in[3];
    float* out = (float*)d_out;

    // ws: WhT bf16 (4 MB) | Wt bf16 (64 KB) | f1 (64 KB) | f2 (64 KB)
    unsigned short* WhT = (unsigned short*)d_ws;
    unsigned short* Wt  = WhT + (size_t)B_ * FOUT * N_;
    float* f1 = (float*)(Wt + (size_t)FOUT * FIN);
    float* f2 = f1 + (size_t)B_ * N_;

    hipLaunchKernelGGL(k0_wt, dim3(FOUT), dim3(FIN), 0, stream, W, Wt);
    hipLaunchKernelGGL(k1_wh, dim3(B_ * N_ / 64), dim3(256), 0, stream,
                       x, Wt, WhT);
    hipLaunchKernelGGL(k1b_f, dim3(B_ * N_ / 256), dim3(256), 0, stream,
                       WhT, a, f1, f2);
    hipLaunchKernelGGL(k2_attn, dim3(B_ * N_ / TI), dim3(256), 0, stream,
                       adj, WhT, f1, f2, out);
}

// Round 4
// 266.587 us; speedup vs baseline: 1.4724x; 1.0605x over previous
//
#include <hip/hip_runtime.h>
#include <hip/hip_bf16.h>
#include <math.h>

#define NEGINF (-9000000000000000.0f)

constexpr int B_   = 8;
constexpr int N_   = 2048;
constexpr int FIN  = 256;
constexpr int FOUT = 128;

constexpr int CH  = 512;          // KB K-chunk length
constexpr int NCH = N_ / CH;      // 4 chunks
constexpr int PR  = CH + 8;       // 520 shorts per P row (pad)
constexpr int XR  = FIN + 8;      // 264 shorts per xs row (pad)

typedef __attribute__((ext_vector_type(8))) short bf16x8;
typedef __attribute__((ext_vector_type(4))) float f32x4;

static __device__ __forceinline__ unsigned short f2bf(float f) {
    __hip_bfloat16 h = __float2bfloat16(f);
    return *reinterpret_cast<unsigned short*>(&h);
}

// ---------------------------------------------------------------------------
// K0: Wt[n][k] = bf16(W[k][n])  (dim-major weight, 64 KB). Tiny.
// ---------------------------------------------------------------------------
__global__ __launch_bounds__(256) void k0_wt(const float* __restrict__ W,
                                             unsigned short* __restrict__ Wt) {
    const int n = blockIdx.x;   // 0..127
    const int k = threadIdx.x;  // 0..255
    Wt[n * FIN + k] = f2bf(W[k * FOUT + n]);
}

// ---------------------------------------------------------------------------
// KA: WhT[b][d][j] = (x@W)^T via MFMA + fused f1/f2 = Wh.a1 / Wh.a2.
// 32 j-rows/block, 512 blocks. A-frags read directly from global Wt (L2-hot,
// 4 quads cover one 64B line per d-row). LDS ~19 KB -> 8 blocks/CU.
// ---------------------------------------------------------------------------
__global__ __launch_bounds__(256) void ka_wh(const float* __restrict__ x,
                                             const unsigned short* __restrict__ Wt,
                                             const float* __restrict__ a,
                                             unsigned short* __restrict__ WhT,
                                             float* __restrict__ f1,
                                             float* __restrict__ f2) {
    __shared__ unsigned short xs[32 * XR];   // 16.5 KB
    __shared__ float as[2 * FOUT];           // 1 KB
    __shared__ float fred[2][4][32];         // 1 KB

    const int tid = threadIdx.x;
    const int j0  = blockIdx.x * 32;         // global flat row base
    const int b   = j0 >> 11;
    const int jb  = j0 & (N_ - 1);

    if (tid < 2 * FOUT) as[tid] = a[tid];
    {   // stage 32 x-rows (fp32 -> bf16), coalesced 32 KB read
        const float4* xsrc = (const float4*)(x + (size_t)j0 * FIN);
#pragma unroll
        for (int t = 0; t < 8; ++t) {
            const int idx = tid + t * 256;
            float4 v = xsrc[idx];
            const int row = idx >> 6, c4 = idx & 63;
            ushort4 u;
            u.x = f2bf(v.x); u.y = f2bf(v.y); u.z = f2bf(v.z); u.w = f2bf(v.w);
            *(ushort4*)&xs[row * XR + c4 * 4] = u;
        }
    }
    __syncthreads();

    const int wave = tid >> 6, lane = tid & 63;
    const int quad = lane >> 4, l16 = lane & 15;

    f32x4 acc[2][2];  // [a-tile(d)][n-tile(j)]
#pragma unroll
    for (int aa = 0; aa < 2; ++aa)
#pragma unroll
        for (int nn = 0; nn < 2; ++nn) acc[aa][nn] = {0.f, 0.f, 0.f, 0.f};

    const unsigned short* wtA0 = Wt + (size_t)(32 * wave + l16) * FIN;
    const unsigned short* wtA1 = wtA0 + 16 * FIN;
#pragma unroll
    for (int ks = 0; ks < FIN / 32; ++ks) {
        const int kof = ks * 32 + quad * 8;
        bf16x8 af0 = *(const bf16x8*)&wtA0[kof];
        bf16x8 af1 = *(const bf16x8*)&wtA1[kof];
        bf16x8 bf0 = *(const bf16x8*)&xs[l16 * XR + kof];
        bf16x8 bf1 = *(const bf16x8*)&xs[(16 + l16) * XR + kof];
        acc[0][0] = __builtin_amdgcn_mfma_f32_16x16x32_bf16(af0, bf0, acc[0][0], 0, 0, 0);
        acc[0][1] = __builtin_amdgcn_mfma_f32_16x16x32_bf16(af0, bf1, acc[0][1], 0, 0, 0);
        acc[1][0] = __builtin_amdgcn_mfma_f32_16x16x32_bf16(af1, bf0, acc[1][0], 0, 0, 0);
        acc[1][1] = __builtin_amdgcn_mfma_f32_16x16x32_bf16(af1, bf1, acc[1][1], 0, 0, 0);
    }

    // store WhT + accumulate f-partials from fp32 accumulators
    unsigned short* dst = WhT + (size_t)b * FOUT * N_;
    float pf[2][2] = {{0.f, 0.f}, {0.f, 0.f}};  // [f1/f2][n-tile]
#pragma unroll
    for (int aa = 0; aa < 2; ++aa)
#pragma unroll
        for (int nn = 0; nn < 2; ++nn)
#pragma unroll
            for (int r = 0; r < 4; ++r) {
                const int d = 32 * wave + 16 * aa + 4 * quad + r;
                const int j = jb + 16 * nn + l16;
                const float v = acc[aa][nn][r];
                dst[(size_t)d * N_ + j] = f2bf(v);
                pf[0][nn] += v * as[d];
                pf[1][nn] += v * as[FOUT + d];
            }
#pragma unroll
    for (int ff = 0; ff < 2; ++ff)
#pragma unroll
        for (int nn = 0; nn < 2; ++nn) {
            float v = pf[ff][nn];
            v += __shfl_xor(v, 16);
            v += __shfl_xor(v, 32);   // sum over quads -> all lanes
            pf[ff][nn] = v;
        }
    if (quad == 0) {
#pragma unroll
        for (int ff = 0; ff < 2; ++ff)
#pragma unroll
            for (int nn = 0; nn < 2; ++nn)
                fred[ff][wave][nn * 16 + l16] = pf[ff][nn];
    }
    __syncthreads();
    if (tid < 64) {
        const int ff = tid >> 5, j32 = tid & 31;
        const float s = fred[ff][0][j32] + fred[ff][1][j32] +
                        fred[ff][2][j32] + fred[ff][3][j32];
        (ff ? f2 : f1)[(size_t)b * N_ + jb + j32] = s;
    }
}

// ---------------------------------------------------------------------------
// KB: flash-style fused masked softmax + P@WhT (MFMA) + ELU.
// 16 rows/block, 1024 blocks, K chunked by 512: LDS ~17 KB -> ~5 blocks/CU.
// Online softmax: running (m,s) per row in wave regs; acc rescaled by alpha
// each chunk. b = blockIdx&7 pins the batch's WhT slab to one XCD L2.
// ---------------------------------------------------------------------------
__global__ __launch_bounds__(256) void kb_attn(const int* __restrict__ adj,
                                               const unsigned short* __restrict__ WhT,
                                               const float* __restrict__ f1,
                                               const float* __restrict__ f2,
                                               float* __restrict__ out) {
    __shared__ unsigned short p[16 * PR];  // 16.6 KB: P chunk, bf16
    __shared__ float alpha_s[16];
    __shared__ float rsum[16];

    const int tid  = threadIdx.x;
    const int b    = blockIdx.x & 7;
    const int i0   = (blockIdx.x >> 3) * 16;
    const int wave = tid >> 6, lane = tid & 63;
    const int quad = lane >> 4, l16 = lane & 15;

    const float4* f2b4 = (const float4*)(f2 + (size_t)b * N_);

    // Phase-A per-wave softmax state for rows 4w..4w+3
    float m_run[4], s_run[4];
#pragma unroll
    for (int r = 0; r < 4; ++r) { m_run[r] = NEGINF; s_run[r] = 0.f; }

    // Phase-B state
    f32x4 acc0 = {0.f, 0.f, 0.f, 0.f}, acc1 = {0.f, 0.f, 0.f, 0.f};
    const int n0 = wave * 32;
    const unsigned short* wB0 = WhT + (size_t)b * FOUT * N_ + (size_t)(n0 + l16) * N_;
    const unsigned short* wB1 = wB0 + (size_t)16 * N_;
    const unsigned short* pA  = &p[l16 * PR];

    for (int c = 0; c < NCH; ++c) {
        // ---- Phase A: wave w -> rows 4w..4w+3, cols [c*512, c*512+512) ----
#pragma unroll
        for (int rr = 0; rr < 4; ++rr) {
            const int ti = wave * 4 + rr;
            const int i  = i0 + ti;
            const float f1i = f1[(size_t)b * N_ + i];
            const int4* arow4 = (const int4*)(adj + ((size_t)b * N_ + i) * (size_t)N_);
            const int c4 = c * (CH / 4);
            int4   av0 = arow4[c4 + lane];
            int4   av1 = arow4[c4 + 64 + lane];
            float4 fv0 = f2b4[c4 + lane];
            float4 fv1 = f2b4[c4 + 64 + lane];

            float e[8];
            e[0] = f1i + fv0.x; e[1] = f1i + fv0.y; e[2] = f1i + fv0.z; e[3] = f1i + fv0.w;
            e[4] = f1i + fv1.x; e[5] = f1i + fv1.y; e[6] = f1i + fv1.z; e[7] = f1i + fv1.w;
#pragma unroll
            for (int q = 0; q < 8; ++q) e[q] = (e[q] >= 0.f) ? e[q] : 2.f * e[q];
            if (av0.x <= 0) e[0] = NEGINF;
            if (av0.y <= 0) e[1] = NEGINF;
            if (av0.z <= 0) e[2] = NEGINF;
            if (av0.w <= 0) e[3] = NEGINF;
            if (av1.x <= 0) e[4] = NEGINF;
            if (av1.y <= 0) e[5] = NEGINF;
            if (av1.z <= 0) e[6] = NEGINF;
            if (av1.w <= 0) e[7] = NEGINF;

            float mx = e[0];
#pragma unroll
            for (int q = 1; q < 8; ++q) mx = fmaxf(mx, e[q]);
#pragma unroll
            for (int o = 32; o; o >>= 1) mx = fmaxf(mx, __shfl_xor(mx, o));

            const float mnew = fmaxf(m_run[rr], mx);
            const float al   = __expf(m_run[rr] - mnew);  // exp(0)=1 / exp(-big)=0
            float pv[8];
            float s8 = 0.f;
#pragma unroll
            for (int q = 0; q < 8; ++q) { pv[q] = __expf(e[q] - mnew); s8 += pv[q]; }
#pragma unroll
            for (int o = 32; o; o >>= 1) s8 += __shfl_xor(s8, o);
            s_run[rr] = s_run[rr] * al + s8;
            m_run[rr] = mnew;

            ushort4 u0, u1;
            u0.x = f2bf(pv[0]); u0.y = f2bf(pv[1]); u0.z = f2bf(pv[2]); u0.w = f2bf(pv[3]);
            u1.x = f2bf(pv[4]); u1.y = f2bf(pv[5]); u1.z = f2bf(pv[6]); u1.w = f2bf(pv[7]);
            *(ushort4*)&p[ti * PR + 4 * lane]       = u0;
            *(ushort4*)&p[ti * PR + 256 + 4 * lane] = u1;
            if (lane == 0) alpha_s[ti] = al;
            if (c == NCH - 1 && lane == 0) rsum[ti] = s_run[rr];
        }
        __syncthreads();

        // ---- Phase B: wave w -> dims 32w..32w+31, this K-chunk ----
#pragma unroll
        for (int r = 0; r < 4; ++r) {
            const float alr = alpha_s[quad * 4 + r];
            acc0[r] *= alr;
            acc1[r] *= alr;
        }
        const int kbase = c * CH;
#pragma unroll
        for (int ks = 0; ks < CH / 32; ++ks) {
            const int kof = ks * 32 + quad * 8;
            bf16x8 afr = *(const bf16x8*)&pA[kof];
            bf16x8 b0  = *(const bf16x8*)&wB0[kbase + kof];
            bf16x8 b1  = *(const bf16x8*)&wB1[kbase + kof];
            acc0 = __builtin_amdgcn_mfma_f32_16x16x32_bf16(afr, b0, acc0, 0, 0, 0);
            acc1 = __builtin_amdgcn_mfma_f32_16x16x32_bf16(afr, b1, acc1, 0, 0, 0);
        }
        __syncthreads();
    }

    // ---- Epilogue: /rowsum, ELU, store (row m = quad*4+r, col n = l16) ----
#pragma unroll
    for (int r = 0; r < 4; ++r) {
        const int m = quad * 4 + r;
        const float inv = 1.f / rsum[m];
        float v0 = acc0[r] * inv;
        float v1 = acc1[r] * inv;
        v0 = (v0 > 0.f) ? v0 : expm1f(v0);
        v1 = (v1 > 0.f) ? v1 : expm1f(v1);
        const size_t base = ((size_t)b * N_ + i0 + m) * FOUT + n0;
        out[base + l16]      = v0;
        out[base + 16 + l16] = v1;
    }
}

// ---------------------------------------------------------------------------
extern "C" void kernel_launch(void* const* d_in, const int* in_sizes, int n_in,
                              void* d_out, int out_size, void* d_ws, size_t ws_size,
                              hipStream_t stream) {
    const float* x   = (const float*)d_in[0];
    const int*   adj = (const int*)d_in[1];
    const float* W   = (const float*)d_in[2];
    const float* a   = (const float*)d_in[3];
    float* out = (float*)d_out;

    // ws: WhT bf16 (4 MB) | Wt bf16 (64 KB) | f1 (64 KB) | f2 (64 KB)
    unsigned short* WhT = (unsigned short*)d_ws;
    unsigned short* Wt  = WhT + (size_t)B_ * FOUT * N_;
    float* f1 = (float*)(Wt + (size_t)FOUT * FIN);
    float* f2 = f1 + (size_t)B_ * N_;

    hipLaunchKernelGGL(k0_wt, dim3(FOUT), dim3(FIN), 0, stream, W, Wt);
    hipLaunchKernelGGL(ka_wh, dim3(B_ * N_ / 32), dim3(256), 0, stream,
                       x, Wt, a, WhT, f1, f2);
    hipLaunchKernelGGL(kb_attn, dim3(B_ * N_ / 16), dim3(256), 0, stream,
                       adj, WhT, f1, f2, out);
}